// Round 7
// baseline (610.323 us; speedup 1.0000x reference)
//
#include <hip/hip_runtime.h>

#define NROW 8192
#define NF   128

typedef float f32x4  __attribute__((ext_vector_type(4)));
typedef int   i32x4  __attribute__((ext_vector_type(4)));
typedef short bf16x8 __attribute__((ext_vector_type(8)));
typedef short bf16x4 __attribute__((ext_vector_type(4)));

__device__ __forceinline__ short f2bf(float f) {
    union { float f; unsigned u; } v; v.f = f;
    unsigned r = v.u + 0x7FFFu + ((v.u >> 16) & 1u);
    return (short)(r >> 16);
}

// Tiled B layout: element (f, r) ->
//   (r>>6)*8192 + (f>>4)*1024 + ((r>>5)&1)*512 + (f&15)*32 + ((r>>3)&3)*8 + (r&7)
// so a B-fragment load (ct, half) is 64 lanes x 16B covering a contiguous 1KB.

// k0: WT[c][k] = bf16(W[k][c])   (128x128, tiny)
__global__ __launch_bounds__(256) void k0_wt(const float* __restrict__ W,
                                             short* __restrict__ WT) {
    int idx = blockIdx.x * 256 + threadIdx.x;
    int c = idx >> 7, k = idx & 127;
    WT[c * NF + k] = f2bf(W[k * NF + c]);
}

// k1: Wh = mo @ W via bf16 MFMA; writes WhT in the TILED layout above,
//     s1 = Wh@a1, s2 = Wh@a2 (f32).
__global__ __launch_bounds__(256) void k1_wh(const float* __restrict__ mo,
        const short* __restrict__ WT,
        const float* __restrict__ a1, const float* __restrict__ a2,
        short* __restrict__ WhT, float* __restrict__ s1g, float* __restrict__ s2g) {
    __shared__ float s_lds[2][32];
    int t = threadIdx.x;
    int w = t >> 6, l = t & 63, lg = l >> 4, lr = l & 15;
    int rows0 = blockIdx.x * 32;
    if (t < 64) s_lds[t >> 5][t & 31] = 0.0f;
    __syncthreads();

    f32x4 acc[2][2] = {}; // [rt][ct]
#pragma unroll
    for (int ks = 0; ks < 4; ++ks) {
        bf16x8 a[2], b[2];
#pragma unroll
        for (int rt = 0; rt < 2; ++rt) {
            const float* ap = mo + (size_t)(rows0 + rt*16 + lr) * NF + ks*32 + lg*8;
            f32x4 x0 = *(const f32x4*)ap;
            f32x4 x1 = *(const f32x4*)(ap + 4);
#pragma unroll
            for (int e = 0; e < 4; ++e) { a[rt][e] = f2bf(x0[e]); a[rt][4+e] = f2bf(x1[e]); }
        }
#pragma unroll
        for (int ct = 0; ct < 2; ++ct) {
            int c = w*32 + ct*16 + lr;
            b[ct] = *(const bf16x8*)(WT + c*NF + ks*32 + lg*8);
        }
#pragma unroll
        for (int rt = 0; rt < 2; ++rt)
#pragma unroll
            for (int ct = 0; ct < 2; ++ct)
                acc[rt][ct] = __builtin_amdgcn_mfma_f32_16x16x32_bf16(a[rt], b[ct], acc[rt][ct], 0, 0, 0);
    }

    // epilogue: C/D layout: col = lane&15, row = (lane>>4)*4 + reg
#pragma unroll
    for (int rt = 0; rt < 2; ++rt) {
        float p1[4] = {0,0,0,0}, p2[4] = {0,0,0,0};
#pragma unroll
        for (int ct = 0; ct < 2; ++ct) {
            int c = w*32 + ct*16 + lr;
            float a1c = a1[c], a2c = a2[c];
            bf16x4 wv;
#pragma unroll
            for (int g = 0; g < 4; ++g) {
                float v = acc[rt][ct][g];
                wv[g] = f2bf(v);
                p1[g] += v * a1c;
                p2[g] += v * a2c;
            }
            int r0 = rows0 + rt*16 + lg*4;
            size_t off = (size_t)(r0 >> 6) * 8192 + (size_t)(c >> 4) * 1024
                       + (size_t)((r0 >> 5) & 1) * 512 + (size_t)(c & 15) * 32
                       + (size_t)((r0 >> 3) & 3) * 8 + (size_t)(r0 & 7);
            *(bf16x4*)(WhT + off) = wv;
        }
#pragma unroll
        for (int off = 1; off < 16; off <<= 1) {
#pragma unroll
            for (int g = 0; g < 4; ++g) {
                p1[g] += __shfl_xor(p1[g], off);
                p2[g] += __shfl_xor(p2[g], off);
            }
        }
        if (lr == 0) {
            int rloc = rt*16 + lg*4;
#pragma unroll
            for (int g = 0; g < 4; ++g) {
                atomicAdd(&s_lds[0][rloc+g], p1[g]);
                atomicAdd(&s_lds[1][rloc+g], p2[g]);
            }
        }
    }
    __syncthreads();
    if (t < 32)       s1g[rows0 + t]        = s_lds[0][t];
    else if (t < 64)  s2g[rows0 + (t - 32)] = s_lds[1][t - 32];
}

// k2: block = 4 waves on the SAME 16 rows, in-block j-split x4, cross-block x S.
// Single-buffered per-wave P tile (same-wave LDS ordering makes dbuf
// unnecessary) -> 17.1KB LDS; launch_bounds(256,6) -> target 6 blocks/CU,
// 24 waves/CU, relying on wave-overlap (not register prefetch) to hide B/L2
// and adj/L3 latency. No barriers in the main loop.
__global__ __launch_bounds__(256, 6) void k2_main(
        const int* __restrict__ adj, const short* __restrict__ WhT,
        const float* __restrict__ s1g, const float* __restrict__ s2g,
        float* __restrict__ numP, float* __restrict__ zP,
        int S, int npb) {
    __shared__ __attribute__((aligned(16))) char smem[17472];
    short* Pl   = (short*)smem;                   // [4][16][72]  (9216 B)
    float* s2l  = (float*)(smem + 9216);          // [2048]       (8192 B)
    float* Lacc = (float*)smem;                   // [2][2048], aliases Pl+s2l
    float* Lz   = (float*)(smem + 17408);         // [16]
#define PL(W_,R_) (Pl + ((W_)*16 + (R_))*72)

    int t = threadIdx.x, w = t >> 6, l = t & 63;
    int lo = l & 15, hi = l >> 4;     // used for both stage and fragment sides
    int b = blockIdx.x, jseg = b % S, rg = b / S;
    int rows0 = rg << 4;
    int j0 = jseg * npb;

    // stage s2 slice + init Lz
    { f32x4* d_ = (f32x4*)s2l; const f32x4* s_ = (const f32x4*)(s2g + j0);
      d_[t] = s_[t]; d_[t + 256] = s_[t + 256]; }
    if (t < 16) Lz[t] = 0.0f;
    __syncthreads();

    int nwt = npb >> 2;               // j span per wave
    int jb  = j0 + w * nwt;
    int NT  = nwt >> 6;

    float s1q[4];
#pragma unroll
    for (int c = 0; c < 4; ++c) s1q[c] = s1g[rows0 + c*4 + hi];

    f32x4 acc[8] = {};
    float zacc[4] = {0.f, 0.f, 0.f, 0.f};

    // adj prefetch: instr c reads rows rows0+c*4+hi, cols jt+lo*4 (4x256B runs)
    i32x4 A[4];
#pragma unroll
    for (int c = 0; c < 4; ++c)
        A[c] = *(const i32x4*)(adj + (size_t)(rows0 + c*4 + hi) * NROW + jb + lo*4);

    for (int it = 0; it < NT; ++it) {
        int jt = jb + (it << 6);
        // --- (1) B tile: 16 coalesced 1KB loads, contiguous 16KB ---
        bf16x8 Bv[8][2];
        const short* tb = WhT + (size_t)(jt >> 6) * 8192 + lo*32 + hi*8;
#pragma unroll
        for (int ct = 0; ct < 8; ++ct) {
            Bv[ct][0] = *(const bf16x8*)(tb + ct*1024);
            Bv[ct][1] = *(const bf16x8*)(tb + ct*1024 + 512);
        }
        // --- (2) exp/mask (prefetched adj, s2 from LDS), bf16 P -> LDS ---
        int jloc = jt - j0;
        f32x4 sv = *(const f32x4*)(s2l + jloc + lo*4);
#pragma unroll
        for (int c = 0; c < 4; ++c) {
            bf16x4 pv;
#pragma unroll
            for (int e = 0; e < 4; ++e) {
                float x  = s1q[c] + sv[e];
                float lk = fmaxf(x, 0.2f * x);
                float p  = __expf(lk);
                p = (A[c][e] > 0) ? p : 0.0f;
                zacc[c] += p;
                pv[e] = f2bf(p);
            }
            *(bf16x4*)(PL(w, c*4 + hi) + lo*4) = pv;
        }
        // --- (3) prefetch next adj tile ---
        if (it + 1 < NT) {
#pragma unroll
            for (int c = 0; c < 4; ++c)
                A[c] = *(const i32x4*)(adj + (size_t)(rows0 + c*4 + hi) * NROW + jt + 64 + lo*4);
        }
        // --- (4) A-frags from LDS (same-wave RAW) ---
        const short* Pr = PL(w, lo);
        bf16x8 fa0 = *(const bf16x8*)(Pr + hi*8);
        bf16x8 fa1 = *(const bf16x8*)(Pr + 32 + hi*8);
        // --- (5) MFMA drains B ---
#pragma unroll
        for (int ct = 0; ct < 8; ++ct) {
            acc[ct] = __builtin_amdgcn_mfma_f32_16x16x32_bf16(fa0, Bv[ct][0], acc[ct], 0, 0, 0);
            acc[ct] = __builtin_amdgcn_mfma_f32_16x16x32_bf16(fa1, Bv[ct][1], acc[ct], 0, 0, 0);
        }
    }

    // --- z: reduce over the 16 lo-lanes (cols), rows = c*4+hi ---
#pragma unroll
    for (int c = 0; c < 4; ++c) {
        zacc[c] += __shfl_xor(zacc[c], 1);
        zacc[c] += __shfl_xor(zacc[c], 2);
        zacc[c] += __shfl_xor(zacc[c], 4);
        zacc[c] += __shfl_xor(zacc[c], 8);
    }
    if (lo == 0) {
#pragma unroll
        for (int c = 0; c < 4; ++c) atomicAdd(&Lz[c*4 + hi], zacc[c]);
    }
    __syncthreads();   // all waves done with Pl/s2l before Lacc writes (alias!)
    if (t < 16) zP[(size_t)jseg * NROW + rows0 + t] = Lz[t];

    // --- acc: tree-reduce 4 waves (identical (lane,ct,g)->(row,col) maps) ---
    if (w >= 2) {
        float* s0 = &Lacc[(w - 2) * 2048];
#pragma unroll
        for (int ct = 0; ct < 8; ++ct) *(f32x4*)(s0 + ct*256 + l*4) = acc[ct];
    }
    __syncthreads();
    if (w < 2) {
        const float* s0 = &Lacc[w * 2048];
#pragma unroll
        for (int ct = 0; ct < 8; ++ct) acc[ct] += *(const f32x4*)(s0 + ct*256 + l*4);
    }
    __syncthreads();
    if (w == 1) {
        float* s0 = &Lacc[0];
#pragma unroll
        for (int ct = 0; ct < 8; ++ct) *(f32x4*)(s0 + ct*256 + l*4) = acc[ct];
    }
    __syncthreads();
    if (w == 0) {
        const float* s0 = &Lacc[0];
        size_t obase = (size_t)jseg * NROW * NF;
#pragma unroll
        for (int ct = 0; ct < 8; ++ct) {
            acc[ct] += *(const f32x4*)(s0 + ct*256 + l*4);
            int cc = ct*16 + lo;
            int r0 = rows0 + hi*4;
#pragma unroll
            for (int g = 0; g < 4; ++g)
                numP[obase + (size_t)(r0 + g) * NF + cc] = acc[ct][g];
        }
    }
#undef PL
}

// k3: out = elu( sum_s num / sum_s z ), vectorized x4
__global__ __launch_bounds__(256) void k3_reduce(const float* __restrict__ numP,
        const float* __restrict__ zP, float* __restrict__ out, int S) {
    int idx = (blockIdx.x * 256 + threadIdx.x) * 4;
    int r = idx >> 7;
    f32x4 num = {};
    float zz = 0.0f;
    for (int s = 0; s < S; ++s) {
        f32x4 v = *(const f32x4*)(numP + (size_t)s * (NROW * NF) + idx);
        num += v;
        zz  += zP[s * NROW + r];
    }
    f32x4 o;
#pragma unroll
    for (int e = 0; e < 4; ++e) {
        float h = num[e] / zz;
        o[e] = (h > 0.0f) ? h : expm1f(h);
    }
    *(f32x4*)(out + idx) = o;
}

extern "C" void kernel_launch(void* const* d_in, const int* in_sizes, int n_in,
                              void* d_out, int out_size, void* d_ws, size_t ws_size,
                              hipStream_t stream) {
    const float* mo  = (const float*)d_in[0];
    const int*   adj = (const int*)d_in[1];
    const float* W   = (const float*)d_in[2];
    const float* a1  = (const float*)d_in[3];
    const float* a2  = (const float*)d_in[4];
    float* out = (float*)d_out;

    char* p = (char*)d_ws;
    short* WT  = (short*)p;  p += (size_t)NF * NF * 2;
    short* WhT = (short*)p;  p += (size_t)NF * NROW * 2;
    float* s1  = (float*)p;  p += (size_t)NROW * 4;
    float* s2  = (float*)p;  p += (size_t)NROW * 4;
    float* zP  = (float*)p;  p += (size_t)4 * NROW * 4;   // reserved for S<=4
    size_t fixed = (size_t)(p - (char*)d_ws);

    int S = 4;
    while (S > 1 && fixed + (size_t)S * NROW * NF * 4 > ws_size) S >>= 1;
    float* numP = (float*)p;
    if (fixed + (size_t)S * NROW * NF * 4 > ws_size) numP = out;  // S==1 in-place fallback

    k0_wt<<<dim3(64), dim3(256), 0, stream>>>(W, WT);
    k1_wh<<<dim3(256), dim3(256), 0, stream>>>(mo, WT, a1, a2, WhT, s1, s2);
    k2_main<<<dim3((NROW / 16) * S), dim3(256), 0, stream>>>(adj, WhT, s1, s2, numP, zP, S, NROW / S);
    k3_reduce<<<dim3(NROW * NF / 1024), dim3(256), 0, stream>>>(numP, zP, out, S);
}

// Round 8
// 225.372 us; speedup vs baseline: 2.7081x; 2.7081x over previous
//
#include <hip/hip_runtime.h>

#define NROW 8192
#define NF   128

typedef float f32x4  __attribute__((ext_vector_type(4)));
typedef int   i32x4  __attribute__((ext_vector_type(4)));
typedef short bf16x8 __attribute__((ext_vector_type(8)));
typedef short bf16x4 __attribute__((ext_vector_type(4)));

__device__ __forceinline__ short f2bf(float f) {
    union { float f; unsigned u; } v; v.f = f;
    unsigned r = v.u + 0x7FFFu + ((v.u >> 16) & 1u);
    return (short)(r >> 16);
}

// Tiled B layout: element (f, r) ->
//   (r>>6)*8192 + (f>>4)*1024 + ((r>>5)&1)*512 + (f&15)*32 + ((r>>3)&3)*8 + (r&7)
// so a B-fragment load (ct, half) is 64 lanes x 16B covering a contiguous 1KB.

// k0: WT[c][k] = bf16(W[k][c])   (128x128, tiny)
__global__ __launch_bounds__(256) void k0_wt(const float* __restrict__ W,
                                             short* __restrict__ WT) {
    int idx = blockIdx.x * 256 + threadIdx.x;
    int c = idx >> 7, k = idx & 127;
    WT[c * NF + k] = f2bf(W[k * NF + c]);
}

// k1: Wh = mo @ W via bf16 MFMA; writes WhT in the TILED layout above,
//     s1 = Wh@a1, s2 = Wh@a2 (f32).
__global__ __launch_bounds__(256) void k1_wh(const float* __restrict__ mo,
        const short* __restrict__ WT,
        const float* __restrict__ a1, const float* __restrict__ a2,
        short* __restrict__ WhT, float* __restrict__ s1g, float* __restrict__ s2g) {
    __shared__ float s_lds[2][32];
    int t = threadIdx.x;
    int w = t >> 6, l = t & 63, lg = l >> 4, lr = l & 15;
    int rows0 = blockIdx.x * 32;
    if (t < 64) s_lds[t >> 5][t & 31] = 0.0f;
    __syncthreads();

    f32x4 acc[2][2] = {}; // [rt][ct]
#pragma unroll
    for (int ks = 0; ks < 4; ++ks) {
        bf16x8 a[2], b[2];
#pragma unroll
        for (int rt = 0; rt < 2; ++rt) {
            const float* ap = mo + (size_t)(rows0 + rt*16 + lr) * NF + ks*32 + lg*8;
            f32x4 x0 = *(const f32x4*)ap;
            f32x4 x1 = *(const f32x4*)(ap + 4);
#pragma unroll
            for (int e = 0; e < 4; ++e) { a[rt][e] = f2bf(x0[e]); a[rt][4+e] = f2bf(x1[e]); }
        }
#pragma unroll
        for (int ct = 0; ct < 2; ++ct) {
            int c = w*32 + ct*16 + lr;
            b[ct] = *(const bf16x8*)(WT + c*NF + ks*32 + lg*8);
        }
#pragma unroll
        for (int rt = 0; rt < 2; ++rt)
#pragma unroll
            for (int ct = 0; ct < 2; ++ct)
                acc[rt][ct] = __builtin_amdgcn_mfma_f32_16x16x32_bf16(a[rt], b[ct], acc[rt][ct], 0, 0, 0);
    }

    // epilogue: C/D layout: col = lane&15, row = (lane>>4)*4 + reg
#pragma unroll
    for (int rt = 0; rt < 2; ++rt) {
        float p1[4] = {0,0,0,0}, p2[4] = {0,0,0,0};
#pragma unroll
        for (int ct = 0; ct < 2; ++ct) {
            int c = w*32 + ct*16 + lr;
            float a1c = a1[c], a2c = a2[c];
            bf16x4 wv;
#pragma unroll
            for (int g = 0; g < 4; ++g) {
                float v = acc[rt][ct][g];
                wv[g] = f2bf(v);
                p1[g] += v * a1c;
                p2[g] += v * a2c;
            }
            int r0 = rows0 + rt*16 + lg*4;
            size_t off = (size_t)(r0 >> 6) * 8192 + (size_t)(c >> 4) * 1024
                       + (size_t)((r0 >> 5) & 1) * 512 + (size_t)(c & 15) * 32
                       + (size_t)((r0 >> 3) & 3) * 8 + (size_t)(r0 & 7);
            *(bf16x4*)(WhT + off) = wv;
        }
#pragma unroll
        for (int off = 1; off < 16; off <<= 1) {
#pragma unroll
            for (int g = 0; g < 4; ++g) {
                p1[g] += __shfl_xor(p1[g], off);
                p2[g] += __shfl_xor(p2[g], off);
            }
        }
        if (lr == 0) {
            int rloc = rt*16 + lg*4;
#pragma unroll
            for (int g = 0; g < 4; ++g) {
                atomicAdd(&s_lds[0][rloc+g], p1[g]);
                atomicAdd(&s_lds[1][rloc+g], p2[g]);
            }
        }
    }
    __syncthreads();
    if (t < 32)       s1g[rows0 + t]        = s_lds[0][t];
    else if (t < 64)  s2g[rows0 + (t - 32)] = s_lds[1][t - 32];
}

// k2: block = 4 waves on the SAME 16 rows, in-block j-split x4, cross-block x S.
// Per iteration: (1) issue B-tile loads (contiguous 16KB, coalesced 1KB each),
// (2) exp/mask from prefetched adj + LDS-resident s2, P->LDS, (3) prefetch next
// adj, (4) A-frags from LDS, (5) MFMA drains B. No barriers in the main loop.
// launch_bounds(256,4): 128-VGPR cap -> 16 waves/CU without spilling
// (bound 6 = 85 VGPR spilled catastrophically: FETCH 190->790MB, 5x slower).
__global__ __launch_bounds__(256, 4) void k2_main(
        const int* __restrict__ adj, const short* __restrict__ WhT,
        const float* __restrict__ s1g, const float* __restrict__ s2g,
        float* __restrict__ numP, float* __restrict__ zP,
        int S, int npb) {
    __shared__ __attribute__((aligned(16))) char smem[18432 + 8192 + 64];
    short* Pl   = (short*)smem;                   // [4][2][16][72]
    float* Lacc = (float*)smem;                   // [2][2048], aliases Pl
    float* s2l  = (float*)(smem + 18432);         // [2048] block's s2 slice
    float* Lz   = (float*)(smem + 18432 + 8192);  // [16]
#define PL(W_,D_,R_) (Pl + (((W_)*2 + (D_))*16 + (R_))*72)

    int t = threadIdx.x, w = t >> 6, l = t & 63;
    int lo = l & 15, hi = l >> 4;     // used for both stage and fragment sides
    int b = blockIdx.x, jseg = b % S, rg = b / S;
    int rows0 = rg << 4;
    int j0 = jseg * npb;

    // stage s2 slice + init Lz
    { f32x4* d_ = (f32x4*)s2l; const f32x4* s_ = (const f32x4*)(s2g + j0);
      d_[t] = s_[t]; d_[t + 256] = s_[t + 256]; }
    if (t < 16) Lz[t] = 0.0f;
    __syncthreads();

    int nwt = npb >> 2;               // j span per wave
    int jb  = j0 + w * nwt;
    int NT  = nwt >> 6;

    float s1q[4];
#pragma unroll
    for (int c = 0; c < 4; ++c) s1q[c] = s1g[rows0 + c*4 + hi];

    f32x4 acc[8] = {};
    float zacc[4] = {0.f, 0.f, 0.f, 0.f};

    // adj prefetch: instr c reads rows rows0+c*4+hi, cols jt+lo*4 (4x256B runs)
    i32x4 A[4];
#pragma unroll
    for (int c = 0; c < 4; ++c)
        A[c] = *(const i32x4*)(adj + (size_t)(rows0 + c*4 + hi) * NROW + jb + lo*4);

    int d = 0;
    for (int it = 0; it < NT; ++it) {
        int jt = jb + (it << 6);
        // --- (1) B tile: 16 coalesced 1KB loads, contiguous 16KB ---
        bf16x8 Bv[8][2];
        const short* tb = WhT + (size_t)(jt >> 6) * 8192 + lo*32 + hi*8;
#pragma unroll
        for (int ct = 0; ct < 8; ++ct) {
            Bv[ct][0] = *(const bf16x8*)(tb + ct*1024);
            Bv[ct][1] = *(const bf16x8*)(tb + ct*1024 + 512);
        }
        // --- (2) exp/mask (prefetched adj, s2 from LDS), bf16 P -> LDS ---
        int jloc = jt - j0;
        f32x4 sv = *(const f32x4*)(s2l + jloc + lo*4);
#pragma unroll
        for (int c = 0; c < 4; ++c) {
            bf16x4 pv;
#pragma unroll
            for (int e = 0; e < 4; ++e) {
                float x  = s1q[c] + sv[e];
                float lk = fmaxf(x, 0.2f * x);
                float p  = __expf(lk);
                p = (A[c][e] > 0) ? p : 0.0f;
                zacc[c] += p;
                pv[e] = f2bf(p);
            }
            *(bf16x4*)(PL(w, d, c*4 + hi) + lo*4) = pv;
        }
        // --- (3) prefetch next adj tile ---
        if (it + 1 < NT) {
#pragma unroll
            for (int c = 0; c < 4; ++c)
                A[c] = *(const i32x4*)(adj + (size_t)(rows0 + c*4 + hi) * NROW + jt + 64 + lo*4);
        }
        // --- (4) A-frags from LDS (same-wave RAW) ---
        const short* Pr = PL(w, d, lo);
        bf16x8 fa0 = *(const bf16x8*)(Pr + hi*8);
        bf16x8 fa1 = *(const bf16x8*)(Pr + 32 + hi*8);
        // --- (5) MFMA drains B ---
#pragma unroll
        for (int ct = 0; ct < 8; ++ct) {
            acc[ct] = __builtin_amdgcn_mfma_f32_16x16x32_bf16(fa0, Bv[ct][0], acc[ct], 0, 0, 0);
            acc[ct] = __builtin_amdgcn_mfma_f32_16x16x32_bf16(fa1, Bv[ct][1], acc[ct], 0, 0, 0);
        }
        d ^= 1;
    }

    // --- z: reduce over the 16 lo-lanes (cols), rows = c*4+hi ---
#pragma unroll
    for (int c = 0; c < 4; ++c) {
        zacc[c] += __shfl_xor(zacc[c], 1);
        zacc[c] += __shfl_xor(zacc[c], 2);
        zacc[c] += __shfl_xor(zacc[c], 4);
        zacc[c] += __shfl_xor(zacc[c], 8);
    }
    if (lo == 0) {
#pragma unroll
        for (int c = 0; c < 4; ++c) atomicAdd(&Lz[c*4 + hi], zacc[c]);
    }
    __syncthreads();   // also separates last Pl reads from Lacc writes (alias!)
    if (t < 16) zP[(size_t)jseg * NROW + rows0 + t] = Lz[t];

    // --- acc: tree-reduce 4 waves (identical (lane,ct,g)->(row,col) maps) ---
    if (w >= 2) {
        float* s0 = &Lacc[(w - 2) * 2048];
#pragma unroll
        for (int ct = 0; ct < 8; ++ct) *(f32x4*)(s0 + ct*256 + l*4) = acc[ct];
    }
    __syncthreads();
    if (w < 2) {
        const float* s0 = &Lacc[w * 2048];
#pragma unroll
        for (int ct = 0; ct < 8; ++ct) acc[ct] += *(const f32x4*)(s0 + ct*256 + l*4);
    }
    __syncthreads();
    if (w == 1) {
        float* s0 = &Lacc[0];
#pragma unroll
        for (int ct = 0; ct < 8; ++ct) *(f32x4*)(s0 + ct*256 + l*4) = acc[ct];
    }
    __syncthreads();
    if (w == 0) {
        const float* s0 = &Lacc[0];
        size_t obase = (size_t)jseg * NROW * NF;
#pragma unroll
        for (int ct = 0; ct < 8; ++ct) {
            acc[ct] += *(const f32x4*)(s0 + ct*256 + l*4);
            int cc = ct*16 + lo;
            int r0 = rows0 + hi*4;
#pragma unroll
            for (int g = 0; g < 4; ++g)
                numP[obase + (size_t)(r0 + g) * NF + cc] = acc[ct][g];
        }
    }
#undef PL
}

// k3: out = elu( sum_s num / sum_s z ), vectorized x4
__global__ __launch_bounds__(256) void k3_reduce(const float* __restrict__ numP,
        const float* __restrict__ zP, float* __restrict__ out, int S) {
    int idx = (blockIdx.x * 256 + threadIdx.x) * 4;
    int r = idx >> 7;
    f32x4 num = {};
    float zz = 0.0f;
    for (int s = 0; s < S; ++s) {
        f32x4 v = *(const f32x4*)(numP + (size_t)s * (NROW * NF) + idx);
        num += v;
        zz  += zP[s * NROW + r];
    }
    f32x4 o;
#pragma unroll
    for (int e = 0; e < 4; ++e) {
        float h = num[e] / zz;
        o[e] = (h > 0.0f) ? h : expm1f(h);
    }
    *(f32x4*)(out + idx) = o;
}

extern "C" void kernel_launch(void* const* d_in, const int* in_sizes, int n_in,
                              void* d_out, int out_size, void* d_ws, size_t ws_size,
                              hipStream_t stream) {
    const float* mo  = (const float*)d_in[0];
    const int*   adj = (const int*)d_in[1];
    const float* W   = (const float*)d_in[2];
    const float* a1  = (const float*)d_in[3];
    const float* a2  = (const float*)d_in[4];
    float* out = (float*)d_out;

    char* p = (char*)d_ws;
    short* WT  = (short*)p;  p += (size_t)NF * NF * 2;
    short* WhT = (short*)p;  p += (size_t)NF * NROW * 2;
    float* s1  = (float*)p;  p += (size_t)NROW * 4;
    float* s2  = (float*)p;  p += (size_t)NROW * 4;
    float* zP  = (float*)p;  p += (size_t)4 * NROW * 4;   // reserved for S<=4
    size_t fixed = (size_t)(p - (char*)d_ws);

    int S = 4;
    while (S > 1 && fixed + (size_t)S * NROW * NF * 4 > ws_size) S >>= 1;
    float* numP = (float*)p;
    if (fixed + (size_t)S * NROW * NF * 4 > ws_size) numP = out;  // S==1 in-place fallback

    k0_wt<<<dim3(64), dim3(256), 0, stream>>>(W, WT);
    k1_wh<<<dim3(256), dim3(256), 0, stream>>>(mo, WT, a1, a2, WhT, s1, s2);
    k2_main<<<dim3((NROW / 16) * S), dim3(256), 0, stream>>>(adj, WhT, s1, s2, numP, zP, S, NROW / S);
    k3_reduce<<<dim3(NROW * NF / 1024), dim3(256), 0, stream>>>(numP, zP, out, S);
}

// Round 9
// 146.413 us; speedup vs baseline: 4.1685x; 1.5393x over previous
//
#include <hip/hip_runtime.h>

#define NROW 8192
#define NF   128

typedef float f32x4  __attribute__((ext_vector_type(4)));
typedef int   i32x4  __attribute__((ext_vector_type(4)));
typedef short bf16x8 __attribute__((ext_vector_type(8)));
typedef short bf16x4 __attribute__((ext_vector_type(4)));
typedef unsigned long long u64;

__device__ __forceinline__ short f2bf(float f) {
    union { float f; unsigned u; } v; v.f = f;
    unsigned r = v.u + 0x7FFFu + ((v.u >> 16) & 1u);
    return (short)(r >> 16);
}

// Tiled B layout: element (f, r) ->
//   (r>>6)*8192 + (f>>4)*1024 + ((r>>5)&1)*512 + (f&15)*32 + ((r>>3)&3)*8 + (r&7)

// k0: WT[c][k] = bf16(W[k][c])   (128x128, tiny)
__global__ __launch_bounds__(256) void k0_wt(const float* __restrict__ W,
                                             short* __restrict__ WT) {
    int idx = blockIdx.x * 256 + threadIdx.x;
    int c = idx >> 7, k = idx & 127;
    WT[c * NF + k] = f2bf(W[k * NF + c]);
}

// k1f: fused. blocks [0,256): Wh = mo@W (MFMA) -> tiled WhT + s1 + s2.
//             blocks [256,16640): adj -> bitmask (the one mandatory 268MB read).
__global__ __launch_bounds__(256) void k1f(const float* __restrict__ mo,
        const short* __restrict__ WT, const float* __restrict__ a1,
        const float* __restrict__ a2, const int* __restrict__ adj,
        short* __restrict__ WhT, float* __restrict__ s1g, float* __restrict__ s2g,
        unsigned short* __restrict__ bm) {
    if (blockIdx.x >= 256) {
        // ---- bitmask part: thread -> 16 cols -> one u16 ----
        int tid = (blockIdx.x - 256) * 256 + threadIdx.x;
        int row = tid >> 9, widx = tid & 511;
        const int* ap = adj + (size_t)row * NROW + widx * 16;
        unsigned m = 0;
#pragma unroll
        for (int k = 0; k < 4; ++k) {
            i32x4 v = *(const i32x4*)(ap + k * 4);
#pragma unroll
            for (int e = 0; e < 4; ++e) m |= (v[e] > 0 ? 1u : 0u) << (k * 4 + e);
        }
        bm[tid] = (unsigned short)m;
        return;
    }
    // ---- Wh part ----
    __shared__ float s_lds[2][32];
    int t = threadIdx.x;
    int w = t >> 6, l = t & 63, lg = l >> 4, lr = l & 15;
    int rows0 = blockIdx.x * 32;
    if (t < 64) s_lds[t >> 5][t & 31] = 0.0f;
    __syncthreads();

    f32x4 acc[2][2] = {};
#pragma unroll
    for (int ks = 0; ks < 4; ++ks) {
        bf16x8 a[2], b[2];
#pragma unroll
        for (int rt = 0; rt < 2; ++rt) {
            const float* ap = mo + (size_t)(rows0 + rt*16 + lr) * NF + ks*32 + lg*8;
            f32x4 x0 = *(const f32x4*)ap;
            f32x4 x1 = *(const f32x4*)(ap + 4);
#pragma unroll
            for (int e = 0; e < 4; ++e) { a[rt][e] = f2bf(x0[e]); a[rt][4+e] = f2bf(x1[e]); }
        }
#pragma unroll
        for (int ct = 0; ct < 2; ++ct) {
            int c = w*32 + ct*16 + lr;
            b[ct] = *(const bf16x8*)(WT + c*NF + ks*32 + lg*8);
        }
#pragma unroll
        for (int rt = 0; rt < 2; ++rt)
#pragma unroll
            for (int ct = 0; ct < 2; ++ct)
                acc[rt][ct] = __builtin_amdgcn_mfma_f32_16x16x32_bf16(a[rt], b[ct], acc[rt][ct], 0, 0, 0);
    }

    // C/D layout: col = lane&15, row = (lane>>4)*4 + reg
#pragma unroll
    for (int rt = 0; rt < 2; ++rt) {
        float p1[4] = {0,0,0,0}, p2[4] = {0,0,0,0};
#pragma unroll
        for (int ct = 0; ct < 2; ++ct) {
            int c = w*32 + ct*16 + lr;
            float a1c = a1[c], a2c = a2[c];
            bf16x4 wv;
#pragma unroll
            for (int g = 0; g < 4; ++g) {
                float v = acc[rt][ct][g];
                wv[g] = f2bf(v);
                p1[g] += v * a1c;
                p2[g] += v * a2c;
            }
            int r0 = rows0 + rt*16 + lg*4;
            size_t off = (size_t)(r0 >> 6) * 8192 + (size_t)(c >> 4) * 1024
                       + (size_t)((r0 >> 5) & 1) * 512 + (size_t)(c & 15) * 32
                       + (size_t)((r0 >> 3) & 3) * 8 + (size_t)(r0 & 7);
            *(bf16x4*)(WhT + off) = wv;
        }
#pragma unroll
        for (int off = 1; off < 16; off <<= 1) {
#pragma unroll
            for (int g = 0; g < 4; ++g) {
                p1[g] += __shfl_xor(p1[g], off);
                p2[g] += __shfl_xor(p2[g], off);
            }
        }
        if (lr == 0) {
            int rloc = rt*16 + lg*4;
#pragma unroll
            for (int g = 0; g < 4; ++g) {
                atomicAdd(&s_lds[0][rloc+g], p1[g]);
                atomicAdd(&s_lds[1][rloc+g], p2[g]);
            }
        }
    }
    __syncthreads();
    if (t < 32)       s1g[rows0 + t]        = s_lds[0][t];
    else if (t < 64)  s2g[rows0 + (t - 32)] = s_lds[1][t - 32];
}

// k2: block = 4 waves on SAME 16 rows, in-block j-split x4, cross-block x S.
// P computed DIRECTLY into MFMA A-fragments: lane's 16 mask bits come from one
// broadcast u64 bitmask load (L1-resident). No LDS P tile, no stage layout.
// Live set ~105 VGPR -> launch_bounds(256,4) without spilling (16 waves/CU).
__global__ __launch_bounds__(256, 4) void k2_main(
        const unsigned short* __restrict__ bm, const short* __restrict__ WhT,
        const float* __restrict__ s1g, const float* __restrict__ s2g,
        float* __restrict__ numP, float* __restrict__ zP,
        int S, int npb) {
    __shared__ __attribute__((aligned(16))) char smem[16448];
    float* Lacc = (float*)smem;              // [2][2048] used after barrier
    float* s2l  = (float*)smem;              // [npb<=2048] during loop (alias)
    float* Lz   = (float*)(smem + 16384);    // [16]

    int t = threadIdx.x, w = t >> 6, l = t & 63;
    int lo = l & 15, hi = l >> 4;
    int b = blockIdx.x, jseg = b % S, rg = b / S;
    int rows0 = rg << 4;
    int j0 = jseg * npb;

    for (int i = t; i < (npb >> 2); i += 256)
        ((f32x4*)s2l)[i] = ((const f32x4*)(s2g + j0))[i];
    if (t < 16) Lz[t] = 0.0f;
    __syncthreads();

    int nwt = npb >> 2;
    int jb  = j0 + w * nwt;
    int NT  = nwt >> 6;

    float s1v = s1g[rows0 + lo];
    const u64* bmrow = (const u64*)bm + (size_t)(rows0 + lo) * (NROW / 64);

    f32x4 acc[8] = {};
    float z = 0.0f;

    u64 bmq = bmrow[jb >> 6];

    for (int it = 0; it < NT; ++it) {
        int jt = jb + (it << 6);
        // --- B tile: 16 coalesced 1KB loads (covered by exp phase below) ---
        bf16x8 Bv[8][2];
        const short* tb = WhT + (size_t)(jt >> 6) * 8192 + lo*32 + hi*8;
#pragma unroll
        for (int ct = 0; ct < 8; ++ct) {
            Bv[ct][0] = *(const bf16x8*)(tb + ct*1024);
            Bv[ct][1] = *(const bf16x8*)(tb + ct*1024 + 512);
        }
        // --- extract this tile's bits, immediately prefetch next word ---
        unsigned blo = (unsigned)(bmq >> (hi * 8)) & 0xffu;
        unsigned bhi = (unsigned)(bmq >> (32 + hi * 8)) & 0xffu;
        if (it + 1 < NT) bmq = bmrow[(jt + 64) >> 6];
        // --- s2 fragment values (broadcast LDS reads) ---
        int jl = jt - j0;
        f32x4 s0a = *(const f32x4*)(s2l + jl + hi*8);
        f32x4 s0b = *(const f32x4*)(s2l + jl + hi*8 + 4);
        f32x4 s1a = *(const f32x4*)(s2l + jl + 32 + hi*8);
        f32x4 s1b = *(const f32x4*)(s2l + jl + 32 + hi*8 + 4);
        // --- exp/mask straight into A-fragments ---
        bf16x8 fa0, fa1;
#pragma unroll
        for (int e = 0; e < 4; ++e) {
            float x, p;
            x = s1v + s0a[e]; p = __expf(fmaxf(x, 0.2f * x));
            p = ((blo >> e) & 1) ? p : 0.0f;      z += p; fa0[e]   = f2bf(p);
            x = s1v + s0b[e]; p = __expf(fmaxf(x, 0.2f * x));
            p = ((blo >> (4+e)) & 1) ? p : 0.0f;  z += p; fa0[4+e] = f2bf(p);
            x = s1v + s1a[e]; p = __expf(fmaxf(x, 0.2f * x));
            p = ((bhi >> e) & 1) ? p : 0.0f;      z += p; fa1[e]   = f2bf(p);
            x = s1v + s1b[e]; p = __expf(fmaxf(x, 0.2f * x));
            p = ((bhi >> (4+e)) & 1) ? p : 0.0f;  z += p; fa1[4+e] = f2bf(p);
        }
        // --- MFMA drains B ---
#pragma unroll
        for (int ct = 0; ct < 8; ++ct) {
            acc[ct] = __builtin_amdgcn_mfma_f32_16x16x32_bf16(fa0, Bv[ct][0], acc[ct], 0, 0, 0);
            acc[ct] = __builtin_amdgcn_mfma_f32_16x16x32_bf16(fa1, Bv[ct][1], acc[ct], 0, 0, 0);
        }
    }

    // --- z: lane's partial is for row lo; reduce across the 4 hi-groups ---
    z += __shfl_xor(z, 16);
    z += __shfl_xor(z, 32);
    if (l < 16) atomicAdd(&Lz[lo], z);
    __syncthreads();   // all waves done with s2l before Lacc writes (alias!)
    if (t < 16) zP[(size_t)jseg * NROW + rows0 + t] = Lz[t];

    // --- acc: tree-reduce 4 waves (identical (lane,ct,g)->(row,col) maps) ---
    if (w >= 2) {
        float* s0 = &Lacc[(w - 2) * 2048];
#pragma unroll
        for (int ct = 0; ct < 8; ++ct) *(f32x4*)(s0 + ct*256 + l*4) = acc[ct];
    }
    __syncthreads();
    if (w < 2) {
        const float* s0 = &Lacc[w * 2048];
#pragma unroll
        for (int ct = 0; ct < 8; ++ct) acc[ct] += *(const f32x4*)(s0 + ct*256 + l*4);
    }
    __syncthreads();
    if (w == 1) {
        float* s0 = &Lacc[0];
#pragma unroll
        for (int ct = 0; ct < 8; ++ct) *(f32x4*)(s0 + ct*256 + l*4) = acc[ct];
    }
    __syncthreads();
    if (w == 0) {
        const float* s0 = &Lacc[0];
        size_t obase = (size_t)jseg * NROW * NF;
#pragma unroll
        for (int ct = 0; ct < 8; ++ct) {
            acc[ct] += *(const f32x4*)(s0 + ct*256 + l*4);
            int cc = ct*16 + lo;
            int r0 = rows0 + hi*4;
#pragma unroll
            for (int g = 0; g < 4; ++g)
                numP[obase + (size_t)(r0 + g) * NF + cc] = acc[ct][g];
        }
    }
}

// k3: out = elu( sum_s num / sum_s z ), vectorized x4
__global__ __launch_bounds__(256) void k3_reduce(const float* __restrict__ numP,
        const float* __restrict__ zP, float* __restrict__ out, int S) {
    int idx = (blockIdx.x * 256 + threadIdx.x) * 4;
    int r = idx >> 7;
    f32x4 num = {};
    float zz = 0.0f;
    for (int s = 0; s < S; ++s) {
        f32x4 v = *(const f32x4*)(numP + (size_t)s * (NROW * NF) + idx);
        num += v;
        zz  += zP[s * NROW + r];
    }
    f32x4 o;
#pragma unroll
    for (int e = 0; e < 4; ++e) {
        float h = num[e] / zz;
        o[e] = (h > 0.0f) ? h : expm1f(h);
    }
    *(f32x4*)(out + idx) = o;
}

extern "C" void kernel_launch(void* const* d_in, const int* in_sizes, int n_in,
                              void* d_out, int out_size, void* d_ws, size_t ws_size,
                              hipStream_t stream) {
    const float* mo  = (const float*)d_in[0];
    const int*   adj = (const int*)d_in[1];
    const float* W   = (const float*)d_in[2];
    const float* a1  = (const float*)d_in[3];
    const float* a2  = (const float*)d_in[4];
    float* out = (float*)d_out;

    char* p = (char*)d_ws;
    short* WT  = (short*)p;  p += (size_t)NF * NF * 2;
    short* WhT = (short*)p;  p += (size_t)NF * NROW * 2;
    float* s1  = (float*)p;  p += (size_t)NROW * 4;
    float* s2  = (float*)p;  p += (size_t)NROW * 4;
    float* zP  = (float*)p;  p += (size_t)8 * NROW * 4;           // S<=8
    unsigned short* bm = (unsigned short*)p; p += (size_t)NROW * (NROW/16) * 2; // 8MB
    size_t fixed = (size_t)(p - (char*)d_ws);

    int S = 4;
    while (S > 1 && fixed + (size_t)S * NROW * NF * 4 > ws_size) S >>= 1;
    float* numP = (float*)p;
    if (fixed + (size_t)S * NROW * NF * 4 > ws_size) numP = out;  // S==1 fallback

    k0_wt<<<dim3(64), dim3(256), 0, stream>>>(W, WT);
    k1f<<<dim3(256 + NROW * (NROW/16) / 256), dim3(256), 0, stream>>>(
        mo, WT, a1, a2, adj, WhT, s1, s2, bm);
    k2_main<<<dim3((NROW / 16) * S), dim3(256), 0, stream>>>(bm, WhT, s1, s2, numP, zP, S, NROW / S);
    k3_reduce<<<dim3(NROW * NF / 1024), dim3(256), 0, stream>>>(numP, zP, out, S);
}

// Round 10
// 121.456 us; speedup vs baseline: 5.0251x; 1.2055x over previous
//
#include <hip/hip_runtime.h>

#define NROW 8192
#define NF   128

typedef float f32x4  __attribute__((ext_vector_type(4)));
typedef int   i32x4  __attribute__((ext_vector_type(4)));
typedef short bf16x8 __attribute__((ext_vector_type(8)));
typedef short bf16x4 __attribute__((ext_vector_type(4)));
typedef unsigned long long u64;

__device__ __forceinline__ short f2bf(float f) {
    union { float f; unsigned u; } v; v.f = f;
    unsigned r = v.u + 0x7FFFu + ((v.u >> 16) & 1u);
    return (short)(r >> 16);
}

// Tiled B layout: element (f, r) ->
//   (r>>6)*8192 + (f>>4)*1024 + ((r>>5)&1)*512 + (f&15)*32 + ((r>>3)&3)*8 + (r&7)

// k0: WT[c][k] = bf16(W[k][c])   (128x128, tiny)
__global__ __launch_bounds__(256) void k0_wt(const float* __restrict__ W,
                                             short* __restrict__ WT) {
    int idx = blockIdx.x * 256 + threadIdx.x;
    int c = idx >> 7, k = idx & 127;
    WT[c * NF + k] = f2bf(W[k * NF + c]);
}

// k1: Wh = mo @ W via bf16 MFMA -> tiled WhT, s1 = Wh@a1, s2 = Wh@a2.
__global__ __launch_bounds__(256) void k1_wh(const float* __restrict__ mo,
        const short* __restrict__ WT,
        const float* __restrict__ a1, const float* __restrict__ a2,
        short* __restrict__ WhT, float* __restrict__ s1g, float* __restrict__ s2g) {
    __shared__ float s_lds[2][32];
    int t = threadIdx.x;
    int w = t >> 6, l = t & 63, lg = l >> 4, lr = l & 15;
    int rows0 = blockIdx.x * 32;
    if (t < 64) s_lds[t >> 5][t & 31] = 0.0f;
    __syncthreads();

    f32x4 acc[2][2] = {};
#pragma unroll
    for (int ks = 0; ks < 4; ++ks) {
        bf16x8 a[2], b[2];
#pragma unroll
        for (int rt = 0; rt < 2; ++rt) {
            const float* ap = mo + (size_t)(rows0 + rt*16 + lr) * NF + ks*32 + lg*8;
            f32x4 x0 = *(const f32x4*)ap;
            f32x4 x1 = *(const f32x4*)(ap + 4);
#pragma unroll
            for (int e = 0; e < 4; ++e) { a[rt][e] = f2bf(x0[e]); a[rt][4+e] = f2bf(x1[e]); }
        }
#pragma unroll
        for (int ct = 0; ct < 2; ++ct) {
            int c = w*32 + ct*16 + lr;
            b[ct] = *(const bf16x8*)(WT + c*NF + ks*32 + lg*8);
        }
#pragma unroll
        for (int rt = 0; rt < 2; ++rt)
#pragma unroll
            for (int ct = 0; ct < 2; ++ct)
                acc[rt][ct] = __builtin_amdgcn_mfma_f32_16x16x32_bf16(a[rt], b[ct], acc[rt][ct], 0, 0, 0);
    }

    // C/D layout: col = lane&15, row = (lane>>4)*4 + reg
#pragma unroll
    for (int rt = 0; rt < 2; ++rt) {
        float p1[4] = {0,0,0,0}, p2[4] = {0,0,0,0};
#pragma unroll
        for (int ct = 0; ct < 2; ++ct) {
            int c = w*32 + ct*16 + lr;
            float a1c = a1[c], a2c = a2[c];
            bf16x4 wv;
#pragma unroll
            for (int g = 0; g < 4; ++g) {
                float v = acc[rt][ct][g];
                wv[g] = f2bf(v);
                p1[g] += v * a1c;
                p2[g] += v * a2c;
            }
            int r0 = rows0 + rt*16 + lg*4;
            size_t off = (size_t)(r0 >> 6) * 8192 + (size_t)(c >> 4) * 1024
                       + (size_t)((r0 >> 5) & 1) * 512 + (size_t)(c & 15) * 32
                       + (size_t)((r0 >> 3) & 3) * 8 + (size_t)(r0 & 7);
            *(bf16x4*)(WhT + off) = wv;
        }
#pragma unroll
        for (int off = 1; off < 16; off <<= 1) {
#pragma unroll
            for (int g = 0; g < 4; ++g) {
                p1[g] += __shfl_xor(p1[g], off);
                p2[g] += __shfl_xor(p2[g], off);
            }
        }
        if (lr == 0) {
            int rloc = rt*16 + lg*4;
#pragma unroll
            for (int g = 0; g < 4; ++g) {
                atomicAdd(&s_lds[0][rloc+g], p1[g]);
                atomicAdd(&s_lds[1][rloc+g], p2[g]);
            }
        }
    }
    __syncthreads();
    if (t < 32)       s1g[rows0 + t]        = s_lds[0][t];
    else if (t < 64)  s2g[rows0 + (t - 32)] = s_lds[1][t - 32];
}

// k2: block = 4 waves on SAME 16 rows, in-block j-split x4, cross-block x S.
// adj is read DIRECTLY (coalesced, lane<->j, one dword load per row per tile;
// every adj byte read exactly once across the grid) and transposed for free by
// __ballot: bit l of ballot(An[r]>0) = mask(row r, j=jt+l). A 16-step cndmask
// routes row lo's u64 to each lane; exp goes straight into MFMA A-fragments.
// B tile split in two 4-ct halves to keep peak VGPR ~116 < 128 (256,4).
__global__ __launch_bounds__(256, 4) void k2_main(
        const int* __restrict__ adj, const short* __restrict__ WhT,
        const float* __restrict__ s1g, const float* __restrict__ s2g,
        float* __restrict__ numP, float* __restrict__ zP,
        int S, int npb) {
    __shared__ __attribute__((aligned(16))) char smem[16448];
    float* Lacc = (float*)smem;              // [2][2048] used after barrier
    float* s2l  = (float*)smem;              // [npb<=2048] during loop (alias)
    float* Lz   = (float*)(smem + 16384);    // [16]

    int t = threadIdx.x, w = t >> 6, l = t & 63;
    int lo = l & 15, hi = l >> 4;
    int b = blockIdx.x, jseg = b % S, rg = b / S;
    int rows0 = rg << 4;
    int j0 = jseg * npb;

    for (int i = t; i < (npb >> 2); i += 256)
        ((f32x4*)s2l)[i] = ((const f32x4*)(s2g + j0))[i];
    if (t < 16) Lz[t] = 0.0f;
    __syncthreads();

    int nwt = npb >> 2;
    int jb  = j0 + w * nwt;
    int NT  = nwt >> 6;

    float s1v = s1g[rows0 + lo];
    // lane's adj stream: row r, col jb + it*64 + l
    const int* arow = adj + (size_t)rows0 * NROW + jb + l;

    f32x4 acc[8] = {};
    float z = 0.0f;

    int An[16];
#pragma unroll
    for (int r = 0; r < 16; ++r) An[r] = arow[r * NROW];

    for (int it = 0; it < NT; ++it) {
        int jt = jb + (it << 6);
        const short* tb = WhT + (size_t)(jt >> 6) * 8192 + lo*32 + hi*8;
        // --- B half 0 (ct 0..3): latency covered by ballot/select loop ---
        bf16x8 Bv0[4][2];
#pragma unroll
        for (int ct = 0; ct < 4; ++ct) {
            Bv0[ct][0] = *(const bf16x8*)(tb + ct*1024);
            Bv0[ct][1] = *(const bf16x8*)(tb + ct*1024 + 512);
        }
        // --- ballot-transpose 16 rows; prefetch next tile's adj; select ---
        u64 bmq = 0;
        int nxt = (it + 1 < NT) ? 1 : 0;
#pragma unroll
        for (int r = 0; r < 16; ++r) {
            u64 br = __ballot(An[r] > 0);
            if (nxt) An[r] = arow[r * NROW + (it + 1) * 64];
            bmq = (lo == r) ? br : bmq;
        }
        // --- B half 1 (ct 4..7): latency covered by exp block below ---
        bf16x8 Bv1[4][2];
#pragma unroll
        for (int ct = 0; ct < 4; ++ct) {
            Bv1[ct][0] = *(const bf16x8*)(tb + (ct+4)*1024);
            Bv1[ct][1] = *(const bf16x8*)(tb + (ct+4)*1024 + 512);
        }
        // --- exp/mask straight into A-fragments ---
        unsigned blo = (unsigned)(bmq >> (hi * 8)) & 0xffu;
        unsigned bhi = (unsigned)(bmq >> (32 + hi * 8)) & 0xffu;
        int jl = jt - j0;
        bf16x8 fa0, fa1;
        {
            f32x4 sa = *(const f32x4*)(s2l + jl + hi*8);
            f32x4 sb = *(const f32x4*)(s2l + jl + hi*8 + 4);
#pragma unroll
            for (int e = 0; e < 4; ++e) {
                float x, p;
                x = s1v + sa[e]; p = __expf(fmaxf(x, 0.2f * x));
                p = ((blo >> e) & 1) ? p : 0.0f;      z += p; fa0[e]   = f2bf(p);
                x = s1v + sb[e]; p = __expf(fmaxf(x, 0.2f * x));
                p = ((blo >> (4+e)) & 1) ? p : 0.0f;  z += p; fa0[4+e] = f2bf(p);
            }
        }
        {
            f32x4 sa = *(const f32x4*)(s2l + jl + 32 + hi*8);
            f32x4 sb = *(const f32x4*)(s2l + jl + 32 + hi*8 + 4);
#pragma unroll
            for (int e = 0; e < 4; ++e) {
                float x, p;
                x = s1v + sa[e]; p = __expf(fmaxf(x, 0.2f * x));
                p = ((bhi >> e) & 1) ? p : 0.0f;      z += p; fa1[e]   = f2bf(p);
                x = s1v + sb[e]; p = __expf(fmaxf(x, 0.2f * x));
                p = ((bhi >> (4+e)) & 1) ? p : 0.0f;  z += p; fa1[4+e] = f2bf(p);
            }
        }
        // --- MFMA: half 0 then half 1 ---
#pragma unroll
        for (int ct = 0; ct < 4; ++ct) {
            acc[ct] = __builtin_amdgcn_mfma_f32_16x16x32_bf16(fa0, Bv0[ct][0], acc[ct], 0, 0, 0);
            acc[ct] = __builtin_amdgcn_mfma_f32_16x16x32_bf16(fa1, Bv0[ct][1], acc[ct], 0, 0, 0);
        }
#pragma unroll
        for (int ct = 0; ct < 4; ++ct) {
            acc[ct+4] = __builtin_amdgcn_mfma_f32_16x16x32_bf16(fa0, Bv1[ct][0], acc[ct+4], 0, 0, 0);
            acc[ct+4] = __builtin_amdgcn_mfma_f32_16x16x32_bf16(fa1, Bv1[ct][1], acc[ct+4], 0, 0, 0);
        }
    }

    // --- z: lane's partial is for row lo; reduce across the 4 hi-groups ---
    z += __shfl_xor(z, 16);
    z += __shfl_xor(z, 32);
    if (l < 16) atomicAdd(&Lz[lo], z);
    __syncthreads();   // all waves done with s2l before Lacc writes (alias!)
    if (t < 16) zP[(size_t)jseg * NROW + rows0 + t] = Lz[t];

    // --- acc: tree-reduce 4 waves (identical (lane,ct,g)->(row,col) maps) ---
    if (w >= 2) {
        float* s0 = &Lacc[(w - 2) * 2048];
#pragma unroll
        for (int ct = 0; ct < 8; ++ct) *(f32x4*)(s0 + ct*256 + l*4) = acc[ct];
    }
    __syncthreads();
    if (w < 2) {
        const float* s0 = &Lacc[w * 2048];
#pragma unroll
        for (int ct = 0; ct < 8; ++ct) acc[ct] += *(const f32x4*)(s0 + ct*256 + l*4);
    }
    __syncthreads();
    if (w == 1) {
        float* s0 = &Lacc[0];
#pragma unroll
        for (int ct = 0; ct < 8; ++ct) *(f32x4*)(s0 + ct*256 + l*4) = acc[ct];
    }
    __syncthreads();
    if (w == 0) {
        const float* s0 = &Lacc[0];
        size_t obase = (size_t)jseg * NROW * NF;
#pragma unroll
        for (int ct = 0; ct < 8; ++ct) {
            acc[ct] += *(const f32x4*)(s0 + ct*256 + l*4);
            int cc = ct*16 + lo;
            int r0 = rows0 + hi*4;
#pragma unroll
            for (int g = 0; g < 4; ++g)
                numP[obase + (size_t)(r0 + g) * NF + cc] = acc[ct][g];
        }
    }
}

// k3: out = elu( sum_s num / sum_s z ), vectorized x4
__global__ __launch_bounds__(256) void k3_reduce(const float* __restrict__ numP,
        const float* __restrict__ zP, float* __restrict__ out, int S) {
    int idx = (blockIdx.x * 256 + threadIdx.x) * 4;
    int r = idx >> 7;
    f32x4 num = {};
    float zz = 0.0f;
    for (int s = 0; s < S; ++s) {
        f32x4 v = *(const f32x4*)(numP + (size_t)s * (NROW * NF) + idx);
        num += v;
        zz  += zP[s * NROW + r];
    }
    f32x4 o;
#pragma unroll
    for (int e = 0; e < 4; ++e) {
        float h = num[e] / zz;
        o[e] = (h > 0.0f) ? h : expm1f(h);
    }
    *(f32x4*)(out + idx) = o;
}

extern "C" void kernel_launch(void* const* d_in, const int* in_sizes, int n_in,
                              void* d_out, int out_size, void* d_ws, size_t ws_size,
                              hipStream_t stream) {
    const float* mo  = (const float*)d_in[0];
    const int*   adj = (const int*)d_in[1];
    const float* W   = (const float*)d_in[2];
    const float* a1  = (const float*)d_in[3];
    const float* a2  = (const float*)d_in[4];
    float* out = (float*)d_out;

    char* p = (char*)d_ws;
    short* WT  = (short*)p;  p += (size_t)NF * NF * 2;
    short* WhT = (short*)p;  p += (size_t)NF * NROW * 2;
    float* s1  = (float*)p;  p += (size_t)NROW * 4;
    float* s2  = (float*)p;  p += (size_t)NROW * 4;
    float* zP  = (float*)p;  p += (size_t)8 * NROW * 4;   // S<=8
    size_t fixed = (size_t)(p - (char*)d_ws);

    int S = 4;
    while (S > 1 && fixed + (size_t)S * NROW * NF * 4 > ws_size) S >>= 1;
    float* numP = (float*)p;
    if (fixed + (size_t)S * NROW * NF * 4 > ws_size) numP = out;  // S==1 fallback

    k0_wt<<<dim3(64), dim3(256), 0, stream>>>(W, WT);
    k1_wh<<<dim3(256), dim3(256), 0, stream>>>(mo, WT, a1, a2, WhT, s1, s2);
    k2_main<<<dim3((NROW / 16) * S), dim3(256), 0, stream>>>(adj, WhT, s1, s2, numP, zP, S, NROW / S);
    k3_reduce<<<dim3(NROW * NF / 1024), dim3(256), 0, stream>>>(numP, zP, out, S);
}